// Round 10
// baseline (386.561 us; speedup 1.0000x reference)
//
#include <hip/hip_runtime.h>

#define V_NODES 327696
#define E_EDGES 1966080
#define C_DIM   64
#define G_NUM   4
#define EPS_GN  1e-5f
#define N_TILES (V_NODES/16)      // 20481 exact
#define SAGE_BLOCKS 2048
#define WAVES_TOTAL (SAGE_BLOCKS*4)
#define FILL_BLOCKS 512
#define H_BLOCKS 2048
#define NB_SCAN 1281              // ceil(V/256)
#define CH_SCAN2 6                // ceil(NB_SCAN/256)
#define PW 520                    // partial row width (floats)
#define STAT_BLOCKS 2048
#define STAT_WAVES (STAT_BLOCKS*4)     // 8192
#define TOTAL_F4 (V_NODES*16)          // 5243136 float4 chunks
#define SW_CHUNK 640                   // float4s per wave (40 nodes)
#define HIST_BLOCKS 960                // 960*256*8 = E
#define RED_BLOCKS 129                 // 129*4 = 516 entries

typedef short bf16x8 __attribute__((ext_vector_type(8)));
typedef float f32x4  __attribute__((ext_vector_type(4)));
typedef unsigned uintx4 __attribute__((ext_vector_type(4)));
typedef int intx4 __attribute__((ext_vector_type(4)));
typedef unsigned short u16x2 __attribute__((ext_vector_type(2)));

__device__ __forceinline__ unsigned short f2bf(float f) {   // RNE f32 -> bf16
    unsigned u = __float_as_uint(f);
    return (unsigned short)((u + 0x7FFFu + ((u >> 16) & 1u)) >> 16);
}
__device__ __forceinline__ float bf2f(unsigned short b) {
    return __uint_as_float(((unsigned)b) << 16);
}
// monotone-u16 encoding of bf16 bits: order(enc)==order(value)
__device__ __forceinline__ unsigned short encbf(float f) {
    unsigned short b = f2bf(f);
    return b ^ (unsigned short)(0x8000u | ((b >> 15) * 0x7FFFu));
}
__device__ __forceinline__ unsigned decp(unsigned e) {      // packed decode x2
    unsigned s = e & 0x80008000u;
    unsigned m = (s >> 15) * 0x7FFFu;
    return e ^ ~m;
}
__device__ __forceinline__ unsigned pkmaxu(unsigned a, unsigned b) {
    u16x2 xa = __builtin_bit_cast(u16x2, a);
    u16x2 xb = __builtin_bit_cast(u16x2, b);
    u16x2 r  = __builtin_elementwise_max(xa, xb);           // v_pk_max_u16
    return __builtin_bit_cast(unsigned, r);
}

// ---------------------------------------------------------------------------
// K_pre (merged): blocks [0,HIST_BLOCKS) in-degree hist + rank (8 independent
// atomic-returns in flight); blocks [HIST_BLOCKS,..) per-(g,c) stats of x
// (wave-contiguous branch-free fast path, partial rows, no global atomics).
// ---------------------------------------------------------------------------
__global__ __launch_bounds__(256) void k_pre(const float* __restrict__ x,
                                             const int* __restrict__ batch,
                                             const int* __restrict__ ei,
                                             int* __restrict__ hist,
                                             unsigned short* __restrict__ rank,
                                             float* __restrict__ partial1) {
    __shared__ float red_s[256], red_q[256], red_c[G_NUM];
    if (blockIdx.x < HIST_BLOCKS) {
        const int t = blockIdx.x * 256 + threadIdx.x;
        const int* dst = ei + E_EDGES;
        const int e0 = t * 4;
        const int e1 = (E_EDGES / 2) + t * 4;
        intx4 a = *(const intx4*)(dst + e0);
        intx4 b = *(const intx4*)(dst + e1);
        int r0 = atomicAdd(&hist[a[0]], 1);
        int r1 = atomicAdd(&hist[a[1]], 1);
        int r2 = atomicAdd(&hist[a[2]], 1);
        int r3 = atomicAdd(&hist[a[3]], 1);
        int r4 = atomicAdd(&hist[b[0]], 1);
        int r5 = atomicAdd(&hist[b[1]], 1);
        int r6 = atomicAdd(&hist[b[2]], 1);
        int r7 = atomicAdd(&hist[b[3]], 1);
        ushort4 wa = { (unsigned short)r0, (unsigned short)r1,
                       (unsigned short)r2, (unsigned short)r3 };
        ushort4 wb = { (unsigned short)r4, (unsigned short)r5,
                       (unsigned short)r6, (unsigned short)r7 };
        *(ushort4*)(rank + e0) = wa;
        *(ushort4*)(rank + e1) = wb;
        return;
    }
    const int t = threadIdx.x;
    red_s[t] = 0.0f; red_q[t] = 0.0f;
    if (t < G_NUM) red_c[t] = 0.0f;
    __syncthreads();
    const int bid  = blockIdx.x - HIST_BLOCKS;
    const int w    = bid * 4 + (t >> 6);
    const int lane = t & 63;
    const int base = w * SW_CHUNK;
    const int end  = (w == STAT_WAVES - 1) ? TOTAL_F4 : base + SW_CHUNK;
    const int c4   = (lane & 15) << 2;
    const bool cntr = (lane & 15) == 0;
    const float4* x4p = (const float4*)x;
    const int g0 = batch[base >> 4];
    const int g1 = batch[(end - 1) >> 4];
    if (g0 == g1 && end == base + SW_CHUNK) {
        float4 su = {0,0,0,0}, qu = {0,0,0,0};
        #pragma unroll
        for (int it = 0; it < 10; it++) {
            float4 v = x4p[base + lane + it * 64];
            su.x += v.x; su.y += v.y; su.z += v.z; su.w += v.w;
            qu.x = fmaf(v.x, v.x, qu.x); qu.y = fmaf(v.y, v.y, qu.y);
            qu.z = fmaf(v.z, v.z, qu.z); qu.w = fmaf(v.w, v.w, qu.w);
        }
        int p = (g0 << 6) + c4;
        atomicAdd(&red_s[p],   su.x); atomicAdd(&red_q[p],   qu.x);
        atomicAdd(&red_s[p+1], su.y); atomicAdd(&red_q[p+1], qu.y);
        atomicAdd(&red_s[p+2], su.z); atomicAdd(&red_q[p+2], qu.z);
        atomicAdd(&red_s[p+3], su.w); atomicAdd(&red_q[p+3], qu.w);
        if (cntr) atomicAdd(&red_c[g0], 10.0f);
    } else {
        for (int idx = base + lane; idx < end; idx += 64) {
            float4 v = x4p[idx];
            int g = batch[idx >> 4];
            int p = (g << 6) + c4;
            atomicAdd(&red_s[p],   v.x); atomicAdd(&red_q[p],   v.x * v.x);
            atomicAdd(&red_s[p+1], v.y); atomicAdd(&red_q[p+1], v.y * v.y);
            atomicAdd(&red_s[p+2], v.z); atomicAdd(&red_q[p+2], v.z * v.z);
            atomicAdd(&red_s[p+3], v.w); atomicAdd(&red_q[p+3], v.w * v.w);
            if (cntr) atomicAdd(&red_c[g], 1.0f);
        }
    }
    __syncthreads();
    float* row = partial1 + (size_t)bid * PW;
    row[t] = red_s[t]; row[256 + t] = red_q[t];
    if (t < G_NUM) row[512 + t] = red_c[t];
}

// ---------------------------------------------------------------------------
// K_rs1 (merged): blocks [0,RED_BLOCKS) reduce partial1 -> sum1/sumsq1/cnt;
//                 blocks [RED_BLOCKS,..) per-256 block sums of hist -> bsum
// ---------------------------------------------------------------------------
__global__ __launch_bounds__(256) void k_rs1(const float* __restrict__ partial1,
                                             const int* __restrict__ hist,
                                             float* __restrict__ outs,
                                             float* __restrict__ outc,
                                             int* __restrict__ bsum) {
    if (blockIdx.x < RED_BLOCKS) {
        int e = blockIdx.x * 4 + (threadIdx.x >> 6);
        int lane = threadIdx.x & 63;
        if (e >= 516) return;
        float s = 0.0f;
        for (int b = lane; b < STAT_BLOCKS; b += 64) s += partial1[(size_t)b * PW + e];
        #pragma unroll
        for (int off = 1; off < 64; off <<= 1) s += __shfl_xor(s, off);
        if (lane == 0) { if (e < 512) outs[e] = s; else outc[e - 512] = s; }
        return;
    }
    __shared__ int s[256];
    int sb = blockIdx.x - RED_BLOCKS;
    int i = sb * 256 + threadIdx.x;
    s[threadIdx.x] = (i < V_NODES) ? hist[i] : 0;
    __syncthreads();
    for (int off = 128; off > 0; off >>= 1) {
        if (threadIdx.x < off) s[threadIdx.x] += s[threadIdx.x + off];
        __syncthreads();
    }
    if (threadIdx.x == 0) bsum[sb] = s[0];
}

// ---------------------------------------------------------------------------
// K_params: block 0 = GraphNorm-1 affine fold + swizzled weight prep;
//           block 1 = exclusive scan of the 1281 block sums
// ---------------------------------------------------------------------------
__global__ __launch_bounds__(256) void k_params(const float* __restrict__ sum,
                                                const float* __restrict__ sumsq,
                                                const float* __restrict__ cnt,
                                                const float* __restrict__ w,
                                                const float* __restrict__ b,
                                                const float* __restrict__ ms,
                                                float* __restrict__ scale,
                                                float* __restrict__ shift,
                                                const float* __restrict__ Wl,
                                                const float* __restrict__ Wr,
                                                char* __restrict__ gWsw,
                                                int* __restrict__ bsum) {
    if (blockIdx.x == 0) {
        int t = threadIdx.x;            // t = g*64 + c
        int g = t >> 6, c = t & 63;
        float n    = cnt[g];
        float mean = sum[t] / n;
        float msq  = sumsq[t] / n;
        float m    = ms[c];
        float var  = msq - 2.0f*m*mean*mean + m*m*mean*mean;
        float inv  = rsqrtf(var + EPS_GN);
        float sc   = w[c] * inv;
        scale[t] = sc;
        shift[t] = b[c] - mean * m * sc;
        for (int i = threadIdx.x; i < C_DIM*C_DIM; i += 256) {
            int k = i >> 6, col = i & 63;          // W[k][col]
            int boff = (col*128 + k*2) ^ ((col & 7) << 4);
            *(unsigned short*)(gWsw + boff)        = f2bf(Wl[i]);
            *(unsigned short*)(gWsw + 8192 + boff) = f2bf(Wr[i]);
        }
    } else {
        __shared__ int s[256];
        int t = threadIdx.x;
        int loc[CH_SCAN2];
        int mysum = 0;
        #pragma unroll
        for (int j = 0; j < CH_SCAN2; j++) {
            int idx = t * CH_SCAN2 + j;
            loc[j] = (idx < NB_SCAN) ? bsum[idx] : 0;
            mysum += loc[j];
        }
        s[t] = mysum;
        __syncthreads();
        for (int off = 1; off < 256; off <<= 1) {
            int tmp = (t >= off) ? s[t - off] : 0;
            __syncthreads();
            s[t] += tmp;
            __syncthreads();
        }
        int ex = s[t] - mysum;
        #pragma unroll
        for (int j = 0; j < CH_SCAN2; j++) {
            int idx = t * CH_SCAN2 + j;
            if (idx < NB_SCAN) { bsum[idx] = ex; ex += loc[j]; }
        }
    }
}

// ---------------------------------------------------------------------------
// K_scan3: per-block exclusive scan + block offset -> offs
// ---------------------------------------------------------------------------
__global__ __launch_bounds__(256) void k_scan3(const int* __restrict__ hist,
                                               const int* __restrict__ bsum,
                                               int* __restrict__ offs) {
    __shared__ int s[256];
    int t = threadIdx.x;
    int i = blockIdx.x * 256 + t;
    int v = (i < V_NODES) ? hist[i] : 0;
    s[t] = v;
    __syncthreads();
    for (int off = 1; off < 256; off <<= 1) {
        int tmp = (t >= off) ? s[t - off] : 0;
        __syncthreads();
        s[t] += tmp;
        __syncthreads();
    }
    int ex = s[t] - v + bsum[blockIdx.x];
    if (i < V_NODES) offs[i] = ex;
    if (i == 0) offs[V_NODES] = E_EDGES;
}

// ---------------------------------------------------------------------------
// K_h_fill (merged): fill blocks do atomic-free CSR fill via rank;
//                    h blocks compute henc = enc(bf16(norm1(x)))
// ---------------------------------------------------------------------------
__global__ __launch_bounds__(256) void k_h_fill(const float* __restrict__ x,
                                                const int* __restrict__ batch,
                                                const float* __restrict__ scale1,
                                                const float* __restrict__ shift1,
                                                unsigned short* __restrict__ henc,
                                                const int* __restrict__ ei,
                                                const unsigned short* __restrict__ rank,
                                                const int* __restrict__ offs,
                                                int* __restrict__ slots) {
    if (blockIdx.x < FILL_BLOCKS) {
        int stride = FILL_BLOCKS * 256;
        for (int e = blockIdx.x * 256 + threadIdx.x; e < E_EDGES; e += stride) {
            int src = ei[e];
            int d   = ei[E_EDGES + e];
            slots[offs[d] + (int)rank[e]] = src;
        }
        return;
    }
    __shared__ float sc[256], sh[256];
    sc[threadIdx.x] = scale1[threadIdx.x];
    sh[threadIdx.x] = shift1[threadIdx.x];
    __syncthreads();
    const int total = V_NODES * 16;
    int bid = blockIdx.x - FILL_BLOCKS;
    int stride = H_BLOCKS * 256;
    const float4* x4 = (const float4*)x;
    ushort4* h4 = (ushort4*)henc;
    for (int i = bid * 256 + threadIdx.x; i < total; i += stride) {
        int v  = i >> 4;
        int c4 = (i & 15) << 2;
        int g  = batch[v];
        int p  = (g << 6) | c4;
        float4 val = x4[i];
        ushort4 o;
        o.x = encbf(fmaf(val.x, sc[p],   sh[p]));
        o.y = encbf(fmaf(val.y, sc[p+1], sh[p+1]));
        o.z = encbf(fmaf(val.z, sc[p+2], sh[p+2]));
        o.w = encbf(fmaf(val.w, sc[p+3], sh[p+3]));
        h4[i] = o;
    }
}

// ---------------------------------------------------------------------------
// K_sage: R8's register-pkmax gather (proven fastest) + dual MFMA GEMM +
// residual/ReLU + stats2 partials. Optional bf16 pre-norm output (bfout).
// ---------------------------------------------------------------------------
__global__ __launch_bounds__(256) void k_sage(const unsigned short* __restrict__ henc,
                                              const float* __restrict__ x,
                                              const int* __restrict__ batch,
                                              const int* __restrict__ offs,
                                              const int* __restrict__ slots,
                                              const char* __restrict__ gWsw,
                                              const float* __restrict__ bl,
                                              float* __restrict__ out,
                                              unsigned short* __restrict__ outbf,
                                              int bfout,
                                              float* __restrict__ partial2) {
    __shared__ char lds_w[16384];          // Wl swizzled at 0, Wr at 8192
    __shared__ float red_s[256], red_q[256];
    {
        const float4* wsrc = (const float4*)gWsw;
        float4* wdst = (float4*)lds_w;
        for (int t = threadIdx.x; t < 1024; t += 256) wdst[t] = wsrc[t];
    }
    red_s[threadIdx.x] = 0.0f; red_q[threadIdx.x] = 0.0f;
    __syncthreads();

    const int lane = threadIdx.x & 63;
    const int wid  = threadIdx.x >> 6;
    const int lg = lane >> 4, lr = lane & 15;
    const char* hbase = (const char*)henc;

    float blv[4];
    #pragma unroll
    for (int cb = 0; cb < 4; cb++) blv[cb] = bl[cb*16 + lr];

    float su[4] = {0,0,0,0}, qu[4] = {0,0,0,0};
    int gc = -1;

    const int gwave = blockIdx.x * 4 + wid;
    for (int tile = gwave; tile < N_TILES; tile += WAVES_TOTAL) {
        const int rbase = tile << 4;
        const int myrow = rbase + lr;
        int st = offs[myrow];
        int en = offs[myrow + 1];

        // root-h loads early (independent of gather)
        const char* hr = hbase + ((unsigned)myrow << 7);
        uintx4 r0 = *(const uintx4*)(hr + lg*16);
        uintx4 r1 = *(const uintx4*)(hr + 64 + lg*16);

        // ---- gather-max: 8 edges/row/step, 16 h-loads in flight ----
        uintx4 mA0 = {0,0,0,0}, mA1 = {0,0,0,0};
        uintx4 mB0 = {0,0,0,0}, mB1 = {0,0,0,0};
        for (int i = st & ~7; __ballot(i < en) != 0ull; i += 8) {
            intx4 qa = *(const intx4*)(slots + i);
            intx4 qb = *(const intx4*)(slots + i + 4);
            uintx4 a0[4], a1[4], b0[4], b1[4];
            #pragma unroll
            for (int e = 0; e < 4; e++) {
                int ia = i + e;
                unsigned idxa = (ia >= st && ia < en) ? (unsigned)qa[e] : (unsigned)V_NODES;
                const char* pa = hbase + ((size_t)idxa << 7);
                a0[e] = *(const uintx4*)(pa + lg*16);
                a1[e] = *(const uintx4*)(pa + 64 + lg*16);
                int ib = i + 4 + e;
                unsigned idxb = (ib >= st && ib < en) ? (unsigned)qb[e] : (unsigned)V_NODES;
                const char* pb = hbase + ((size_t)idxb << 7);
                b0[e] = *(const uintx4*)(pb + lg*16);
                b1[e] = *(const uintx4*)(pb + 64 + lg*16);
            }
            #pragma unroll
            for (int e = 0; e < 4; e++) {
                #pragma unroll
                for (int j = 0; j < 4; j++) {
                    mA0[j] = pkmaxu(mA0[j], a0[e][j]);
                    mA1[j] = pkmaxu(mA1[j], a1[e][j]);
                    mB0[j] = pkmaxu(mB0[j], b0[e][j]);
                    mB1[j] = pkmaxu(mB1[j], b1[e][j]);
                }
            }
        }
        bool has = en > st;
        uintx4 d0, d1;
        #pragma unroll
        for (int j = 0; j < 4; j++) {
            unsigned m0 = pkmaxu(mA0[j], mB0[j]);
            unsigned m1 = pkmaxu(mA1[j], mB1[j]);
            d0[j] = has ? decp(m0) : 0u;           // no in-edges -> 0.0
            d1[j] = has ? decp(m1) : 0u;
            r0[j] = decp(r0[j]);
            r1[j] = decp(r1[j]);
        }
        bf16x8 a_agg0 = __builtin_bit_cast(bf16x8, d0);
        bf16x8 a_agg1 = __builtin_bit_cast(bf16x8, d1);
        bf16x8 a_h0   = __builtin_bit_cast(bf16x8, r0);
        bf16x8 a_h1   = __builtin_bit_cast(bf16x8, r1);

        // ---- dual GEMM via MFMA, B-frags from swizzled LDS ----
        f32x4 acc[4];
        #pragma unroll
        for (int cb = 0; cb < 4; cb++) {
            acc[cb] = (f32x4){0.f,0.f,0.f,0.f};
            int wrow = cb*16 + lr;
            int sw   = (wrow & 7) << 4;
            int o0   = (wrow*128 +      lg*16) ^ sw;
            int o1   = (wrow*128 + 64 + lg*16) ^ sw;
            bf16x8 wl0 = *(const bf16x8*)(lds_w + o0);
            bf16x8 wl1 = *(const bf16x8*)(lds_w + o1);
            bf16x8 wr0 = *(const bf16x8*)(lds_w + 8192 + o0);
            bf16x8 wr1 = *(const bf16x8*)(lds_w + 8192 + o1);
            acc[cb] = __builtin_amdgcn_mfma_f32_16x16x32_bf16(a_agg0, wl0, acc[cb], 0,0,0);
            acc[cb] = __builtin_amdgcn_mfma_f32_16x16x32_bf16(a_agg1, wl1, acc[cb], 0,0,0);
            acc[cb] = __builtin_amdgcn_mfma_f32_16x16x32_bf16(a_h0,   wr0, acc[cb], 0,0,0);
            acc[cb] = __builtin_amdgcn_mfma_f32_16x16x32_bf16(a_h1,   wr1, acc[cb], 0,0,0);
        }

        // ---- epilogue: bias + residual + ReLU + write + stats ----
        int g0 = batch[rbase], g15 = batch[rbase + 15];
        if (g0 == g15) {
            if (g0 != gc) {
                if (gc >= 0) {
                    #pragma unroll
                    for (int cb = 0; cb < 4; cb++) {
                        atomicAdd(&red_s[(gc<<6) + cb*16 + lr], su[cb]);
                        atomicAdd(&red_q[(gc<<6) + cb*16 + lr], qu[cb]);
                        su[cb] = 0.0f; qu[cb] = 0.0f;
                    }
                }
                gc = g0;
            }
            #pragma unroll
            for (int r = 0; r < 4; r++) {
                int row = rbase + lg*4 + r;
                #pragma unroll
                for (int cb = 0; cb < 4; cb++) {
                    int col = cb*16 + lr;
                    float xv = x[(size_t)row * C_DIM + col];
                    float o  = fmaxf(xv + acc[cb][r] + blv[cb], 0.0f);
                    if (bfout) outbf[(size_t)row * C_DIM + col] = f2bf(o);
                    else       out[(size_t)row * C_DIM + col] = o;
                    su[cb] += o; qu[cb] = fmaf(o, o, qu[cb]);
                }
            }
        } else {                                   // boundary tile (3 of 20481)
            #pragma unroll
            for (int r = 0; r < 4; r++) {
                int row = rbase + lg*4 + r;
                int g   = batch[row];
                #pragma unroll
                for (int cb = 0; cb < 4; cb++) {
                    int col = cb*16 + lr;
                    float xv = x[(size_t)row * C_DIM + col];
                    float o  = fmaxf(xv + acc[cb][r] + blv[cb], 0.0f);
                    if (bfout) outbf[(size_t)row * C_DIM + col] = f2bf(o);
                    else       out[(size_t)row * C_DIM + col] = o;
                    int p = (g << 6) | col;
                    atomicAdd(&red_s[p], o);
                    atomicAdd(&red_q[p], o * o);
                }
            }
        }
    }
    if (gc >= 0) {
        #pragma unroll
        for (int cb = 0; cb < 4; cb++) {
            atomicAdd(&red_s[(gc<<6) + cb*16 + lr], su[cb]);
            atomicAdd(&red_q[(gc<<6) + cb*16 + lr], qu[cb]);
        }
    }
    __syncthreads();
    float* row = partial2 + (size_t)blockIdx.x * PW;
    row[threadIdx.x]       = red_s[threadIdx.x];
    row[256 + threadIdx.x] = red_q[threadIdx.x];
}

// ---------------------------------------------------------------------------
// K_red2p: reduce partial2 AND fold GraphNorm-2 params directly (wave/(g,c))
// ---------------------------------------------------------------------------
__global__ __launch_bounds__(256) void k_red2p(const float* __restrict__ partial2,
                                               const float* __restrict__ cnt,
                                               const float* __restrict__ w,
                                               const float* __restrict__ b,
                                               const float* __restrict__ ms,
                                               float* __restrict__ scale2,
                                               float* __restrict__ shift2) {
    int e = blockIdx.x * 4 + (threadIdx.x >> 6);    // 0..255 = g*64+c
    int lane = threadIdx.x & 63;
    float s = 0.0f, q = 0.0f;
    for (int bb = lane; bb < SAGE_BLOCKS; bb += 64) {
        s += partial2[(size_t)bb * PW + e];
        q += partial2[(size_t)bb * PW + 256 + e];
    }
    #pragma unroll
    for (int off = 1; off < 64; off <<= 1) {
        s += __shfl_xor(s, off);
        q += __shfl_xor(q, off);
    }
    if (lane == 0) {
        int g = e >> 6, c = e & 63;
        float n    = cnt[g];
        float mean = s / n;
        float msq  = q / n;
        float m    = ms[c];
        float var  = msq - 2.0f*m*mean*mean + m*m*mean*mean;
        float inv  = rsqrtf(var + EPS_GN);
        float sc   = w[c] * inv;
        scale2[e] = sc;
        shift2[e] = b[c] - mean * m * sc;
    }
}

// ---------------------------------------------------------------------------
// K_final: final GraphNorm affine. bfin: read bf16 pre-norm (42MB), write f32;
//          else in-place on f32 out.
// ---------------------------------------------------------------------------
__global__ __launch_bounds__(256) void k_final(float* __restrict__ out,
                                               const unsigned short* __restrict__ outbf,
                                               int bfin,
                                               const int* __restrict__ batch,
                                               const float* __restrict__ scale2,
                                               const float* __restrict__ shift2) {
    __shared__ float sc[256], sh[256];
    sc[threadIdx.x] = scale2[threadIdx.x];
    sh[threadIdx.x] = shift2[threadIdx.x];
    __syncthreads();
    const int total = V_NODES * 16;
    int stride = gridDim.x * 256;
    float4* o4 = (float4*)out;
    if (bfin) {
        const ushort4* ob4 = (const ushort4*)outbf;
        for (int i = blockIdx.x * 256 + threadIdx.x; i < total; i += stride) {
            int v  = i >> 4;
            int c4 = (i & 15) << 2;
            int g  = batch[v];
            int p  = (g << 6) | c4;
            ushort4 u = ob4[i];
            float4 res;
            res.x = fmaf(bf2f(u.x), sc[p],   sh[p]);
            res.y = fmaf(bf2f(u.y), sc[p+1], sh[p+1]);
            res.z = fmaf(bf2f(u.z), sc[p+2], sh[p+2]);
            res.w = fmaf(bf2f(u.w), sc[p+3], sh[p+3]);
            o4[i] = res;
        }
    } else {
        for (int i = blockIdx.x * 256 + threadIdx.x; i < total; i += stride) {
            int v  = i >> 4;
            int c4 = (i & 15) << 2;
            int g  = batch[v];
            int p  = (g << 6) | c4;
            float4 val = o4[i];
            val.x = fmaf(val.x, sc[p],   sh[p]);
            val.y = fmaf(val.y, sc[p+1], sh[p+1]);
            val.z = fmaf(val.z, sc[p+2], sh[p+2]);
            val.w = fmaf(val.w, sc[p+3], sh[p+3]);
            o4[i] = val;
        }
    }
}

// ---------------------------------------------------------------------------
extern "C" void kernel_launch(void* const* d_in, const int* in_sizes, int n_in,
                              void* d_out, int out_size, void* d_ws, size_t ws_size,
                              hipStream_t stream) {
    const float* x     = (const float*)d_in[0];
    const int*   ei    = (const int*)  d_in[1];
    const int*   batch = (const int*)  d_in[2];
    const float* n1w   = (const float*)d_in[3];
    const float* n1b   = (const float*)d_in[4];
    const float* n1ms  = (const float*)d_in[5];
    const float* Wl    = (const float*)d_in[6];
    const float* blv   = (const float*)d_in[7];
    const float* Wr    = (const float*)d_in[8];
    const float* n2w   = (const float*)d_in[9];
    const float* n2b   = (const float*)d_in[10];
    const float* n2ms  = (const float*)d_in[11];
    float* out = (float*)d_out;

    // ---- workspace layout (core ~66 MB; optional outbf +42 MB at the end) ----
    char* w = (char*)d_ws;
    unsigned short* henc = (unsigned short*)w; w += (size_t)(V_NODES + 1) * C_DIM * 2; // +dummy row (zeroed)
    int* slots           = (int*)w;            w += (size_t)E_EDGES * 4 + 64;
    int* hist            = (int*)w;            w += (size_t)V_NODES * 4;
    int* offs            = (int*)w;            w += (size_t)(V_NODES + 1) * 4 + 12;
    unsigned short* rank = (unsigned short*)w; w += (size_t)E_EDGES * 2;
    int* bsum            = (int*)w;            w += 1536 * 4;
    char* gWsw           = w;                  w += 16384;
    float* partial1      = (float*)w;          w += (size_t)STAT_BLOCKS * PW * 4;
    float* partial2      = (float*)w;          w += (size_t)SAGE_BLOCKS * PW * 4;
    float* stats  = (float*)w;                 w += 2048 * 4;
    float* sum1   = stats;          // 256
    float* sumsq1 = stats + 256;    // 256
    float* cnt    = stats + 512;    // 4 (+pad 60)
    float* scale1 = stats + 576;
    float* shift1 = stats + 832;
    float* scale2 = stats + 1088;
    float* shift2 = stats + 1344;
    unsigned short* outbf = (unsigned short*)w;
    size_t need_bf = (size_t)(w - (char*)d_ws) + (size_t)V_NODES * C_DIM * 2;
    int bfout = (ws_size >= need_bf) ? 1 : 0;

    hipMemsetAsync(hist, 0, (size_t)V_NODES * sizeof(int), stream);
    hipMemsetAsync(henc + (size_t)V_NODES * C_DIM, 0, C_DIM * 2, stream); // dummy row

    k_pre   <<<HIST_BLOCKS + STAT_BLOCKS, 256, 0, stream>>>(x, batch, ei, hist, rank, partial1);
    k_rs1   <<<RED_BLOCKS + NB_SCAN, 256, 0, stream>>>(partial1, hist, sum1, cnt, bsum);
    k_params<<<2,    256, 0, stream>>>(sum1, sumsq1, cnt, n1w, n1b, n1ms,
                                       scale1, shift1, Wl, Wr, gWsw, bsum);
    k_scan3 <<<NB_SCAN, 256, 0, stream>>>(hist, bsum, offs);
    k_h_fill<<<FILL_BLOCKS + H_BLOCKS, 256, 0, stream>>>(x, batch, scale1, shift1,
                                       henc, ei, rank, offs, slots);
    k_sage  <<<SAGE_BLOCKS, 256, 0, stream>>>(henc, x, batch, offs, slots,
                                       gWsw, blv, out, outbf, bfout, partial2);
    k_red2p <<<64,   256, 0, stream>>>(partial2, cnt, n2w, n2b, n2ms, scale2, shift2);
    k_final <<<2048, 256, 0, stream>>>(out, outbf, bfout, batch, scale2, shift2);
}

// Round 11
// 293.610 us; speedup vs baseline: 1.3166x; 1.3166x over previous
//
#include <hip/hip_runtime.h>

#define V_NODES 327696
#define E_EDGES 1966080
#define C_DIM   64
#define G_NUM   4
#define EPS_GN  1e-5f
#define N_TILES (V_NODES/16)      // 20481 exact
#define SAGE_BLOCKS 2048
#define WAVES_TOTAL (SAGE_BLOCKS*4)
#define H_BLOCKS 2048
#define PW 520                    // partial row width (floats)
#define STAT_BLOCKS 2048
#define STAT_WAVES (STAT_BLOCKS*4)     // 8192
#define TOTAL_F4 (V_NODES*16)          // 5243136 float4 chunks
#define SW_CHUNK 640                   // float4s per wave (40 nodes)
#define RED_BLOCKS 129                 // 129*4 = 516 entries
// ---- bucket-radix CSR build ----
#define BSH 11                         // bucket = dst >> 11
#define BKSZ 2048                      // dsts per bucket
#define NBUCK 161                      // ceil(V / 2048)
#define AB_BLOCKS 480                  // 480 blocks * 4096 edges = E exactly

typedef short bf16x8 __attribute__((ext_vector_type(8)));
typedef float f32x4  __attribute__((ext_vector_type(4)));
typedef unsigned uintx4 __attribute__((ext_vector_type(4)));
typedef int intx4 __attribute__((ext_vector_type(4)));
typedef unsigned short u16x2 __attribute__((ext_vector_type(2)));

__device__ __forceinline__ unsigned short f2bf(float f) {   // RNE f32 -> bf16
    unsigned u = __float_as_uint(f);
    return (unsigned short)((u + 0x7FFFu + ((u >> 16) & 1u)) >> 16);
}
__device__ __forceinline__ float bf2f(unsigned short b) {
    return __uint_as_float(((unsigned)b) << 16);
}
// monotone-u16 encoding of bf16 bits: order(enc)==order(value); finite -> >0
__device__ __forceinline__ unsigned short encbf(float f) {
    unsigned short b = f2bf(f);
    return b ^ (unsigned short)(0x8000u | ((b >> 15) * 0x7FFFu));
}
__device__ __forceinline__ unsigned decp(unsigned e) {      // packed decode x2
    unsigned s = e & 0x80008000u;
    unsigned m = (s >> 15) * 0x7FFFu;
    return e ^ ~m;
}
__device__ __forceinline__ unsigned pkmaxu(unsigned a, unsigned b) {
    u16x2 xa = __builtin_bit_cast(u16x2, a);
    u16x2 xb = __builtin_bit_cast(u16x2, b);
    u16x2 r  = __builtin_elementwise_max(xa, xb);           // v_pk_max_u16
    return __builtin_bit_cast(unsigned, r);
}

// ---------------------------------------------------------------------------
// K_pre2 (merged): blocks [0,AB_BLOCKS) = A1 per-block 161-bin bucket hist of
// dst (LDS, no global atomics); blocks [AB_BLOCKS,..) = per-(g,c) stats of x
// (wave-contiguous branch-free fast path, partial rows).
// ---------------------------------------------------------------------------
__global__ __launch_bounds__(256) void k_pre2(const float* __restrict__ x,
                                              const int* __restrict__ batch,
                                              const int* __restrict__ ei,
                                              int* __restrict__ blkhist,
                                              float* __restrict__ partial1) {
    const int t = threadIdx.x;
    if (blockIdx.x < AB_BLOCKS) {
        __shared__ int bh[NBUCK];
        for (int j = t; j < NBUCK; j += 256) bh[j] = 0;
        __syncthreads();
        const int* dst = ei + E_EDGES;
        const int qb = blockIdx.x * 1024;
        #pragma unroll
        for (int k = 0; k < 4; k++) {
            intx4 q = *(const intx4*)(dst + (qb + k*256 + t) * 4);
            atomicAdd(&bh[q[0] >> BSH], 1);
            atomicAdd(&bh[q[1] >> BSH], 1);
            atomicAdd(&bh[q[2] >> BSH], 1);
            atomicAdd(&bh[q[3] >> BSH], 1);
        }
        __syncthreads();
        for (int j = t; j < NBUCK; j += 256)
            blkhist[j * AB_BLOCKS + blockIdx.x] = bh[j];
        return;
    }
    __shared__ float red_s[256], red_q[256], red_c[G_NUM];
    red_s[t] = 0.0f; red_q[t] = 0.0f;
    if (t < G_NUM) red_c[t] = 0.0f;
    __syncthreads();
    const int bid  = blockIdx.x - AB_BLOCKS;
    const int w    = bid * 4 + (t >> 6);
    const int lane = t & 63;
    const int base = w * SW_CHUNK;
    const int end  = (w == STAT_WAVES - 1) ? TOTAL_F4 : base + SW_CHUNK;
    const int c4   = (lane & 15) << 2;
    const bool cntr = (lane & 15) == 0;
    const float4* x4p = (const float4*)x;
    const int g0 = batch[base >> 4];
    const int g1 = batch[(end - 1) >> 4];
    if (g0 == g1 && end == base + SW_CHUNK) {
        float4 su = {0,0,0,0}, qu = {0,0,0,0};
        #pragma unroll
        for (int it = 0; it < 10; it++) {
            float4 v = x4p[base + lane + it * 64];
            su.x += v.x; su.y += v.y; su.z += v.z; su.w += v.w;
            qu.x = fmaf(v.x, v.x, qu.x); qu.y = fmaf(v.y, v.y, qu.y);
            qu.z = fmaf(v.z, v.z, qu.z); qu.w = fmaf(v.w, v.w, qu.w);
        }
        int p = (g0 << 6) + c4;
        atomicAdd(&red_s[p],   su.x); atomicAdd(&red_q[p],   qu.x);
        atomicAdd(&red_s[p+1], su.y); atomicAdd(&red_q[p+1], qu.y);
        atomicAdd(&red_s[p+2], su.z); atomicAdd(&red_q[p+2], qu.z);
        atomicAdd(&red_s[p+3], su.w); atomicAdd(&red_q[p+3], qu.w);
        if (cntr) atomicAdd(&red_c[g0], 10.0f);
    } else {
        for (int idx = base + lane; idx < end; idx += 64) {
            float4 v = x4p[idx];
            int g = batch[idx >> 4];
            int p = (g << 6) + c4;
            atomicAdd(&red_s[p],   v.x); atomicAdd(&red_q[p],   v.x * v.x);
            atomicAdd(&red_s[p+1], v.y); atomicAdd(&red_q[p+1], v.y * v.y);
            atomicAdd(&red_s[p+2], v.z); atomicAdd(&red_q[p+2], v.z * v.z);
            atomicAdd(&red_s[p+3], v.w); atomicAdd(&red_q[p+3], v.w * v.w);
            if (cntr) atomicAdd(&red_c[g], 1.0f);
        }
    }
    __syncthreads();
    float* row = partial1 + (size_t)bid * PW;
    row[t] = red_s[t]; row[256 + t] = red_q[t];
    if (t < G_NUM) row[512 + t] = red_c[t];
}

// ---------------------------------------------------------------------------
// K_rs2 (merged): blocks [0,RED_BLOCKS) reduce partial1 -> sum1/sumsq1/cnt;
// block RED_BLOCKS = A2: bucket totals + exclusive scan; rewrite blkhist in
// place to per-(bucket,block) global write bases; emit bbase[].
// ---------------------------------------------------------------------------
__global__ __launch_bounds__(256) void k_rs2(const float* __restrict__ partial1,
                                             int* __restrict__ blkhist,
                                             float* __restrict__ outs,
                                             float* __restrict__ outc,
                                             int* __restrict__ bbase) {
    if (blockIdx.x < RED_BLOCKS) {
        int e = blockIdx.x * 4 + (threadIdx.x >> 6);
        int lane = threadIdx.x & 63;
        if (e >= 516) return;
        float s = 0.0f;
        for (int b = lane; b < STAT_BLOCKS; b += 64) s += partial1[(size_t)b * PW + e];
        #pragma unroll
        for (int off = 1; off < 64; off <<= 1) s += __shfl_xor(s, off);
        if (lane == 0) { if (e < 512) outs[e] = s; else outc[e - 512] = s; }
        return;
    }
    // ---- A2 (single block) ----
    __shared__ int tot[256];
    const int t = threadIdx.x;
    int s = 0;
    if (t < NBUCK) {
        for (int i = 0; i < AB_BLOCKS; i++) s += blkhist[t * AB_BLOCKS + i];
    }
    tot[t] = s;
    __syncthreads();
    for (int off = 1; off < 256; off <<= 1) {      // Hillis-Steele inclusive
        int tmp = (t >= off) ? tot[t - off] : 0;
        __syncthreads();
        tot[t] += tmp;
        __syncthreads();
    }
    int ex = tot[t] - s;                            // exclusive prefix
    if (t < NBUCK) {
        bbase[t] = ex;
        int run = ex;
        for (int i = 0; i < AB_BLOCKS; i++) {
            int c = blkhist[t * AB_BLOCKS + i];
            blkhist[t * AB_BLOCKS + i] = run;
            run += c;
        }
    }
    if (t == 0) bbase[NBUCK] = E_EDGES;
}

// ---------------------------------------------------------------------------
// K_params: GraphNorm-1 affine fold + swizzled bf16 weight prep (1 block)
// ---------------------------------------------------------------------------
__global__ __launch_bounds__(256) void k_params(const float* __restrict__ sum,
                                                const float* __restrict__ sumsq,
                                                const float* __restrict__ cnt,
                                                const float* __restrict__ w,
                                                const float* __restrict__ b,
                                                const float* __restrict__ ms,
                                                float* __restrict__ scale,
                                                float* __restrict__ shift,
                                                const float* __restrict__ Wl,
                                                const float* __restrict__ Wr,
                                                char* __restrict__ gWsw) {
    int t = threadIdx.x;            // t = g*64 + c
    int g = t >> 6, c = t & 63;
    float n    = cnt[g];
    float mean = sum[t] / n;
    float msq  = sumsq[t] / n;
    float m    = ms[c];
    float var  = msq - 2.0f*m*mean*mean + m*m*mean*mean;
    float inv  = rsqrtf(var + EPS_GN);
    float sc   = w[c] * inv;
    scale[t] = sc;
    shift[t] = b[c] - mean * m * sc;
    for (int i = threadIdx.x; i < C_DIM*C_DIM; i += 256) {
        int k = i >> 6, col = i & 63;          // W[k][col]
        int boff = (col*128 + k*2) ^ ((col & 7) << 4);
        *(unsigned short*)(gWsw + boff)        = f2bf(Wl[i]);
        *(unsigned short*)(gWsw + 8192 + boff) = f2bf(Wr[i]);
    }
}

// ---------------------------------------------------------------------------
// K_h_a3 (merged): blocks [0,AB_BLOCKS) = A3 scatter edges into dst-buckets
// (LDS cursors from blkhist bases; writes (dst,src) u64 to ebuf);
// blocks [AB_BLOCKS,..) = henc = enc(bf16(norm1(x))).
// ---------------------------------------------------------------------------
__global__ __launch_bounds__(256) void k_h_a3(const float* __restrict__ x,
                                              const int* __restrict__ batch,
                                              const float* __restrict__ scale1,
                                              const float* __restrict__ shift1,
                                              unsigned short* __restrict__ henc,
                                              const int* __restrict__ ei,
                                              const int* __restrict__ blkhist,
                                              unsigned long long* __restrict__ ebuf) {
    const int t = threadIdx.x;
    if (blockIdx.x < AB_BLOCKS) {
        __shared__ int cur[NBUCK];
        for (int j = t; j < NBUCK; j += 256)
            cur[j] = blkhist[j * AB_BLOCKS + blockIdx.x];
        __syncthreads();
        const int qb = blockIdx.x * 1024;
        #pragma unroll
        for (int k = 0; k < 4; k++) {
            int q = qb + k*256 + t;
            intx4 sq = *(const intx4*)(ei + q*4);
            intx4 dq = *(const intx4*)(ei + E_EDGES + q*4);
            #pragma unroll
            for (int j = 0; j < 4; j++) {
                int pos = atomicAdd(&cur[dq[j] >> BSH], 1);
                ebuf[pos] = ((unsigned long long)(unsigned)dq[j] << 32)
                          | (unsigned)sq[j];
            }
        }
        return;
    }
    __shared__ float sc[256], sh[256];
    sc[t] = scale1[t];
    sh[t] = shift1[t];
    __syncthreads();
    const int total = V_NODES * 16;
    int bid = blockIdx.x - AB_BLOCKS;
    int stride = H_BLOCKS * 256;
    const float4* x4 = (const float4*)x;
    ushort4* h4 = (ushort4*)henc;
    for (int i = bid * 256 + t; i < total; i += stride) {
        int v  = i >> 4;
        int c4 = (i & 15) << 2;
        int g  = batch[v];
        int p  = (g << 6) | c4;
        float4 val = x4[i];
        ushort4 o;
        o.x = encbf(fmaf(val.x, sc[p],   sh[p]));
        o.y = encbf(fmaf(val.y, sc[p+1], sh[p+1]));
        o.z = encbf(fmaf(val.z, sc[p+2], sh[p+2]));
        o.w = encbf(fmaf(val.w, sc[p+3], sh[p+3]));
        h4[i] = o;
    }
}

// ---------------------------------------------------------------------------
// K_B: one block per bucket. Pass1: LDS 2048-bin in-degree hist (no returns).
// Block-scan -> offs (global CSR) + LDS cursors. Pass2: slots[pos]=src with
// LDS atomic returns; slot writes land in a ~48KB L2-hot window.
// ---------------------------------------------------------------------------
__global__ __launch_bounds__(256) void k_B(const unsigned long long* __restrict__ ebuf,
                                           const int* __restrict__ bbase,
                                           int* __restrict__ offs,
                                           int* __restrict__ slots) {
    __shared__ int h[BKSZ];
    __shared__ int ts[256];
    const int b = blockIdx.x;
    const int t = threadIdx.x;
    for (int j = t; j < BKSZ; j += 256) h[j] = 0;
    __syncthreads();
    const int eb = bbase[b], ee = bbase[b + 1];
    const int vbase = b << BSH;
    // ---- pass 1: count (4-deep batched loads) ----
    int i = eb + t;
    for (; i + 768 < ee; i += 1024) {
        unsigned long long v0 = ebuf[i];
        unsigned long long v1 = ebuf[i + 256];
        unsigned long long v2 = ebuf[i + 512];
        unsigned long long v3 = ebuf[i + 768];
        atomicAdd(&h[(int)(v0 >> 32) - vbase], 1);
        atomicAdd(&h[(int)(v1 >> 32) - vbase], 1);
        atomicAdd(&h[(int)(v2 >> 32) - vbase], 1);
        atomicAdd(&h[(int)(v3 >> 32) - vbase], 1);
    }
    for (; i < ee; i += 256)
        atomicAdd(&h[(int)(ebuf[i] >> 32) - vbase], 1);
    __syncthreads();
    // ---- block exclusive scan of h[0..2047] ----
    int loc[8]; int ssum = 0;
    #pragma unroll
    for (int k = 0; k < 8; k++) { loc[k] = h[t*8 + k]; ssum += loc[k]; }
    ts[t] = ssum;
    __syncthreads();
    for (int off = 1; off < 256; off <<= 1) {
        int tmp = (t >= off) ? ts[t - off] : 0;
        __syncthreads();
        ts[t] += tmp;
        __syncthreads();
    }
    int run = ts[t] - ssum;
    int dn = V_NODES - vbase; if (dn > BKSZ) dn = BKSZ;
    #pragma unroll
    for (int k = 0; k < 8; k++) {
        int j = t*8 + k;
        int pref = run; run += loc[k];
        h[j] = eb + pref;                      // absolute slot cursor
        if (j < dn) offs[vbase + j] = eb + pref;
    }
    if (b == NBUCK - 1 && t == 0) offs[V_NODES] = E_EDGES;
    __syncthreads();
    // ---- pass 2: fill slots ----
    i = eb + t;
    for (; i + 768 < ee; i += 1024) {
        unsigned long long v0 = ebuf[i];
        unsigned long long v1 = ebuf[i + 256];
        unsigned long long v2 = ebuf[i + 512];
        unsigned long long v3 = ebuf[i + 768];
        slots[atomicAdd(&h[(int)(v0 >> 32) - vbase], 1)] = (int)(unsigned)v0;
        slots[atomicAdd(&h[(int)(v1 >> 32) - vbase], 1)] = (int)(unsigned)v1;
        slots[atomicAdd(&h[(int)(v2 >> 32) - vbase], 1)] = (int)(unsigned)v2;
        slots[atomicAdd(&h[(int)(v3 >> 32) - vbase], 1)] = (int)(unsigned)v3;
    }
    for (; i < ee; i += 256) {
        unsigned long long v = ebuf[i];
        slots[atomicAdd(&h[(int)(v >> 32) - vbase], 1)] = (int)(unsigned)v;
    }
}

// ---------------------------------------------------------------------------
// K_sage (template, compile-time output dtype): R8's register-pkmax gather +
// dual MFMA GEMM + residual/ReLU + stats2 partials.
// ---------------------------------------------------------------------------
template<int BFOUT>
__global__ __launch_bounds__(256) void k_sage(const unsigned short* __restrict__ henc,
                                              const float* __restrict__ x,
                                              const int* __restrict__ batch,
                                              const int* __restrict__ offs,
                                              const int* __restrict__ slots,
                                              const char* __restrict__ gWsw,
                                              const float* __restrict__ bl,
                                              float* __restrict__ out,
                                              unsigned short* __restrict__ outbf,
                                              float* __restrict__ partial2) {
    __shared__ char lds_w[16384];          // Wl swizzled at 0, Wr at 8192
    __shared__ float red_s[256], red_q[256];
    {
        const float4* wsrc = (const float4*)gWsw;
        float4* wdst = (float4*)lds_w;
        for (int t = threadIdx.x; t < 1024; t += 256) wdst[t] = wsrc[t];
    }
    red_s[threadIdx.x] = 0.0f; red_q[threadIdx.x] = 0.0f;
    __syncthreads();

    const int lane = threadIdx.x & 63;
    const int wid  = threadIdx.x >> 6;
    const int lg = lane >> 4, lr = lane & 15;
    const char* hbase = (const char*)henc;

    float blv[4];
    #pragma unroll
    for (int cb = 0; cb < 4; cb++) blv[cb] = bl[cb*16 + lr];

    float su[4] = {0,0,0,0}, qu[4] = {0,0,0,0};
    int gc = -1;

    const int gwave = blockIdx.x * 4 + wid;
    for (int tile = gwave; tile < N_TILES; tile += WAVES_TOTAL) {
        const int rbase = tile << 4;
        const int myrow = rbase + lr;
        int st = offs[myrow];
        int en = offs[myrow + 1];

        const char* hr = hbase + ((unsigned)myrow << 7);
        uintx4 r0 = *(const uintx4*)(hr + lg*16);
        uintx4 r1 = *(const uintx4*)(hr + 64 + lg*16);

        // ---- gather-max: 8 edges/row/step, 16 h-loads in flight ----
        uintx4 mA0 = {0,0,0,0}, mA1 = {0,0,0,0};
        uintx4 mB0 = {0,0,0,0}, mB1 = {0,0,0,0};
        for (int i = st & ~7; __ballot(i < en) != 0ull; i += 8) {
            intx4 qa = *(const intx4*)(slots + i);
            intx4 qb = *(const intx4*)(slots + i + 4);
            uintx4 a0[4], a1[4], b0[4], b1[4];
            #pragma unroll
            for (int e = 0; e < 4; e++) {
                int ia = i + e;
                unsigned idxa = (ia >= st && ia < en) ? (unsigned)qa[e] : (unsigned)V_NODES;
                const char* pa = hbase + ((size_t)idxa << 7);
                a0[e] = *(const uintx4*)(pa + lg*16);
                a1[e] = *(const uintx4*)(pa + 64 + lg*16);
                int ib = i + 4 + e;
                unsigned idxb = (ib >= st && ib < en) ? (unsigned)qb[e] : (unsigned)V_NODES;
                const char* pb = hbase + ((size_t)idxb << 7);
                b0[e] = *(const uintx4*)(pb + lg*16);
                b1[e] = *(const uintx4*)(pb + 64 + lg*16);
            }
            #pragma unroll
            for (int e = 0; e < 4; e++) {
                #pragma unroll
                for (int j = 0; j < 4; j++) {
                    mA0[j] = pkmaxu(mA0[j], a0[e][j]);
                    mA1[j] = pkmaxu(mA1[j], a1[e][j]);
                    mB0[j] = pkmaxu(mB0[j], b0[e][j]);
                    mB1[j] = pkmaxu(mB1[j], b1[e][j]);
                }
            }
        }
        bool has = en > st;
        uintx4 d0, d1;
        #pragma unroll
        for (int j = 0; j < 4; j++) {
            unsigned m0 = pkmaxu(mA0[j], mB0[j]);
            unsigned m1 = pkmaxu(mA1[j], mB1[j]);
            d0[j] = has ? decp(m0) : 0u;           // no in-edges -> 0.0
            d1[j] = has ? decp(m1) : 0u;
            r0[j] = decp(r0[j]);
            r1[j] = decp(r1[j]);
        }
        bf16x8 a_agg0 = __builtin_bit_cast(bf16x8, d0);
        bf16x8 a_agg1 = __builtin_bit_cast(bf16x8, d1);
        bf16x8 a_h0   = __builtin_bit_cast(bf16x8, r0);
        bf16x8 a_h1   = __builtin_bit_cast(bf16x8, r1);

        f32x4 acc[4];
        #pragma unroll
        for (int cb = 0; cb < 4; cb++) {
            acc[cb] = (f32x4){0.f,0.f,0.f,0.f};
            int wrow = cb*16 + lr;
            int sw   = (wrow & 7) << 4;
            int o0   = (wrow*128 +      lg*16) ^ sw;
            int o1   = (wrow*128 + 64 + lg*16) ^ sw;
            bf16x8 wl0 = *(const bf16x8*)(lds_w + o0);
            bf16x8 wl1 = *(const bf16x8*)(lds_w + o1);
            bf16x8 wr0 = *(const bf16x8*)(lds_w + 8192 + o0);
            bf16x8 wr1 = *(const bf16x8*)(lds_w + 8192 + o1);
            acc[cb] = __builtin_amdgcn_mfma_f32_16x16x32_bf16(a_agg0, wl0, acc[cb], 0,0,0);
            acc[cb] = __builtin_amdgcn_mfma_f32_16x16x32_bf16(a_agg1, wl1, acc[cb], 0,0,0);
            acc[cb] = __builtin_amdgcn_mfma_f32_16x16x32_bf16(a_h0,   wr0, acc[cb], 0,0,0);
            acc[cb] = __builtin_amdgcn_mfma_f32_16x16x32_bf16(a_h1,   wr1, acc[cb], 0,0,0);
        }

        int g0 = batch[rbase], g15 = batch[rbase + 15];
        if (g0 == g15) {
            if (g0 != gc) {
                if (gc >= 0) {
                    #pragma unroll
                    for (int cb = 0; cb < 4; cb++) {
                        atomicAdd(&red_s[(gc<<6) + cb*16 + lr], su[cb]);
                        atomicAdd(&red_q[(gc<<6) + cb*16 + lr], qu[cb]);
                        su[cb] = 0.0f; qu[cb] = 0.0f;
                    }
                }
                gc = g0;
            }
            #pragma unroll
            for (int r = 0; r < 4; r++) {
                int row = rbase + lg*4 + r;
                #pragma unroll
                for (int cb = 0; cb < 4; cb++) {
                    int col = cb*16 + lr;
                    float xv = x[(size_t)row * C_DIM + col];
                    float o  = fmaxf(xv + acc[cb][r] + blv[cb], 0.0f);
                    if constexpr (BFOUT) outbf[(size_t)row * C_DIM + col] = f2bf(o);
                    else                 out[(size_t)row * C_DIM + col] = o;
                    su[cb] += o; qu[cb] = fmaf(o, o, qu[cb]);
                }
            }
        } else {                                   // boundary tile (3 of 20481)
            #pragma unroll
            for (int r = 0; r < 4; r++) {
                int row = rbase + lg*4 + r;
                int g   = batch[row];
                #pragma unroll
                for (int cb = 0; cb < 4; cb++) {
                    int col = cb*16 + lr;
                    float xv = x[(size_t)row * C_DIM + col];
                    float o  = fmaxf(xv + acc[cb][r] + blv[cb], 0.0f);
                    if constexpr (BFOUT) outbf[(size_t)row * C_DIM + col] = f2bf(o);
                    else                 out[(size_t)row * C_DIM + col] = o;
                    int p = (g << 6) | col;
                    atomicAdd(&red_s[p], o);
                    atomicAdd(&red_q[p], o * o);
                }
            }
        }
    }
    if (gc >= 0) {
        #pragma unroll
        for (int cb = 0; cb < 4; cb++) {
            atomicAdd(&red_s[(gc<<6) + cb*16 + lr], su[cb]);
            atomicAdd(&red_q[(gc<<6) + cb*16 + lr], qu[cb]);
        }
    }
    __syncthreads();
    float* row = partial2 + (size_t)blockIdx.x * PW;
    row[threadIdx.x]       = red_s[threadIdx.x];
    row[256 + threadIdx.x] = red_q[threadIdx.x];
}

// ---------------------------------------------------------------------------
// K_red2p: reduce partial2 AND fold GraphNorm-2 params directly (wave/(g,c))
// ---------------------------------------------------------------------------
__global__ __launch_bounds__(256) void k_red2p(const float* __restrict__ partial2,
                                               const float* __restrict__ cnt,
                                               const float* __restrict__ w,
                                               const float* __restrict__ b,
                                               const float* __restrict__ ms,
                                               float* __restrict__ scale2,
                                               float* __restrict__ shift2) {
    int e = blockIdx.x * 4 + (threadIdx.x >> 6);    // 0..255 = g*64+c
    int lane = threadIdx.x & 63;
    float s = 0.0f, q = 0.0f;
    for (int bb = lane; bb < SAGE_BLOCKS; bb += 64) {
        s += partial2[(size_t)bb * PW + e];
        q += partial2[(size_t)bb * PW + 256 + e];
    }
    #pragma unroll
    for (int off = 1; off < 64; off <<= 1) {
        s += __shfl_xor(s, off);
        q += __shfl_xor(q, off);
    }
    if (lane == 0) {
        int g = e >> 6, c = e & 63;
        float n    = cnt[g];
        float mean = s / n;
        float msq  = q / n;
        float m    = ms[c];
        float var  = msq - 2.0f*m*mean*mean + m*m*mean*mean;
        float inv  = rsqrtf(var + EPS_GN);
        float sc   = w[c] * inv;
        scale2[e] = sc;
        shift2[e] = b[c] - mean * m * sc;
    }
}

// ---------------------------------------------------------------------------
// K_final (template): final GraphNorm affine; bf16 or f32 pre-norm input.
// ---------------------------------------------------------------------------
template<int BFIN>
__global__ __launch_bounds__(256) void k_final(float* __restrict__ out,
                                               const unsigned short* __restrict__ outbf,
                                               const int* __restrict__ batch,
                                               const float* __restrict__ scale2,
                                               const float* __restrict__ shift2) {
    __shared__ float sc[256], sh[256];
    sc[threadIdx.x] = scale2[threadIdx.x];
    sh[threadIdx.x] = shift2[threadIdx.x];
    __syncthreads();
    const int total = V_NODES * 16;
    int stride = gridDim.x * 256;
    float4* o4 = (float4*)out;
    const ushort4* ob4 = (const ushort4*)outbf;
    for (int i = blockIdx.x * 256 + threadIdx.x; i < total; i += stride) {
        int v  = i >> 4;
        int c4 = (i & 15) << 2;
        int g  = batch[v];
        int p  = (g << 6) | c4;
        float4 val;
        if constexpr (BFIN) {
            ushort4 u = ob4[i];
            val.x = bf2f(u.x); val.y = bf2f(u.y);
            val.z = bf2f(u.z); val.w = bf2f(u.w);
        } else {
            val = o4[i];
        }
        val.x = fmaf(val.x, sc[p],   sh[p]);
        val.y = fmaf(val.y, sc[p+1], sh[p+1]);
        val.z = fmaf(val.z, sc[p+2], sh[p+2]);
        val.w = fmaf(val.w, sc[p+3], sh[p+3]);
        o4[i] = val;
    }
}

// ---------------------------------------------------------------------------
extern "C" void kernel_launch(void* const* d_in, const int* in_sizes, int n_in,
                              void* d_out, int out_size, void* d_ws, size_t ws_size,
                              hipStream_t stream) {
    const float* x     = (const float*)d_in[0];
    const int*   ei    = (const int*)  d_in[1];
    const int*   batch = (const int*)  d_in[2];
    const float* n1w   = (const float*)d_in[3];
    const float* n1b   = (const float*)d_in[4];
    const float* n1ms  = (const float*)d_in[5];
    const float* Wl    = (const float*)d_in[6];
    const float* blv   = (const float*)d_in[7];
    const float* Wr    = (const float*)d_in[8];
    const float* n2w   = (const float*)d_in[9];
    const float* n2b   = (const float*)d_in[10];
    const float* n2ms  = (const float*)d_in[11];
    float* out = (float*)d_out;

    // ---- workspace layout; tail region = ebuf (phases A/B) then outbf (sage+) ----
    char* w = (char*)d_ws;
    unsigned short* henc = (unsigned short*)w; w += (size_t)(V_NODES + 1) * C_DIM * 2; // +dummy row
    int* slots           = (int*)w;            w += (size_t)E_EDGES * 4 + 64;          // +pad for quad reads
    int* offs            = (int*)w;            w += (size_t)(V_NODES + 1) * 4 + 12;
    int* blkhist         = (int*)w;            w += (size_t)NBUCK * AB_BLOCKS * 4;
    int* bbase           = (int*)w;            w += 256 * 4;
    char* gWsw           = w;                  w += 16384;
    float* partial1      = (float*)w;          w += (size_t)STAT_BLOCKS * PW * 4;
    float* partial2      = (float*)w;          w += (size_t)SAGE_BLOCKS * PW * 4;
    float* stats  = (float*)w;                 w += 2048 * 4;
    float* sum1   = stats;          // 256
    float* sumsq1 = stats + 256;    // 256
    float* cnt    = stats + 512;    // 4 (+pad)
    float* scale1 = stats + 576;
    float* shift1 = stats + 832;
    float* scale2 = stats + 1088;
    float* shift2 = stats + 1344;
    // tail: ebuf (16 MB, dead after k_B) overlaid by outbf (42 MB, sage onward)
    unsigned long long* ebuf = (unsigned long long*)w;
    unsigned short* outbf    = (unsigned short*)w;
    size_t core = (size_t)(w - (char*)d_ws);
    size_t need_bf = core + (size_t)V_NODES * C_DIM * 2;   // outbf variant
    int bfout = (ws_size >= need_bf) ? 1 : 0;

    hipMemsetAsync(henc + (size_t)V_NODES * C_DIM, 0, C_DIM * 2, stream); // dummy row

    k_pre2  <<<AB_BLOCKS + STAT_BLOCKS, 256, 0, stream>>>(x, batch, ei, blkhist, partial1);
    k_rs2   <<<RED_BLOCKS + 1, 256, 0, stream>>>(partial1, blkhist, sum1, cnt, bbase);
    k_params<<<1,    256, 0, stream>>>(sum1, sumsq1, cnt, n1w, n1b, n1ms,
                                       scale1, shift1, Wl, Wr, gWsw);
    k_h_a3  <<<AB_BLOCKS + H_BLOCKS, 256, 0, stream>>>(x, batch, scale1, shift1,
                                       henc, ei, blkhist, ebuf);
    k_B     <<<NBUCK, 256, 0, stream>>>(ebuf, bbase, offs, slots);
    if (bfout) {
        k_sage<1><<<SAGE_BLOCKS, 256, 0, stream>>>(henc, x, batch, offs, slots,
                                       gWsw, blv, out, outbf, partial2);
    } else {
        k_sage<0><<<SAGE_BLOCKS, 256, 0, stream>>>(henc, x, batch, offs, slots,
                                       gWsw, blv, out, outbf, partial2);
    }
    k_red2p <<<64,   256, 0, stream>>>(partial2, cnt, n2w, n2b, n2ms, scale2, shift2);
    if (bfout) k_final<1><<<2048, 256, 0, stream>>>(out, outbf, batch, scale2, shift2);
    else       k_final<0><<<2048, 256, 0, stream>>>(out, outbf, batch, scale2, shift2);
}